// Round 5
// baseline (250.994 us; speedup 1.0000x reference)
//
#include <hip/hip_runtime.h>

#define BATCH 256
#define SEQ   512
#define NT    64
#define PITCH 68    // ldsT pitch in halves (final transpose only)
#define SLICE 8704  // per-wave LDS slice bytes: max(32*64*4, 64*68*2) = 8704

typedef __attribute__((ext_vector_type(8)))  short bf16x8;
typedef __attribute__((ext_vector_type(16))) float f32x16;
typedef __attribute__((ext_vector_type(4)))  float f32x4;
typedef __attribute__((ext_vector_type(2)))  float f32x2;

static __device__ __forceinline__ unsigned pk_bf16(float lo, float hi) {
    // dst = lo.bf16 | (hi.bf16 << 16), truncation — single v_perm_b32
    return __builtin_amdgcn_perm(__float_as_uint(hi), __float_as_uint(lo), 0x07060302u);
}
static __device__ __forceinline__ short bf16_trunc(float v) {
    return (short)(__float_as_uint(v) >> 16);
}

// ---------------------------------------------------------------------------
// Core per-wave chunk routine (R1-proven inner loop, verbatim).
// One wave owns one (batch, chunk) chain on a private LDS slice.
// ---------------------------------------------------------------------------
template<int PCH_, int CLEN_>
static __device__ __forceinline__ void chunk_wave(
    const float* __restrict__ emissions,
    const float* __restrict__ trans,
    unsigned short* __restrict__ mats,
    unsigned char* slice,          // SLICE bytes, 16B aligned, private to wave
    int b, int c, int lane)
{
    float*          w_flat = (float*)slice;
    unsigned short* ldsT   = (unsigned short*)slice;

    const int h  = lane >> 5;
    const int ml = lane & 31;

    const int s0 = c * CLEN_;
    int L = (SEQ - 1) - s0; if (L > CLEN_) L = CLEN_;

    const float* em_b = emissions + (size_t)b * SEQ * NT;

    // ---- staging: w = exp(em) for steps s0+1 .. s0+L, vectorized float4 ----
    {
        const float4* src = (const float4*)(em_b + (size_t)(s0 + 1) * NT);
        float4*       dst = (float4*)w_flat;
        const int total4 = L * (NT / 4);
        for (int i = lane; i < total4; i += 64) {
            float4 v = src[i];
            v.x = __expf(v.x); v.y = __expf(v.y);
            v.z = __expf(v.z); v.w = __expf(v.w);
            dst[i] = v;
        }
    }

    // Permuted A: Af[mt][kk] slot (h,j) = Es[mt*32+ml][r], Es = E^T * 2^-7,
    // r = 32*(kk>>1) + 16*(kk&1) + (j&3) + 8*(j>>2) + 4h
    bf16x8 Af[2][4];
#pragma unroll
    for (int mt = 0; mt < 2; ++mt) {
        int m = mt * 32 + ml;
#pragma unroll
        for (int kk = 0; kk < 4; ++kk) {
            bf16x8 f;
#pragma unroll
            for (int j = 0; j < 8; ++j) {
                int r = 32 * (kk >> 1) + 16 * (kk & 1) + (j & 3) + 8 * (j >> 2) + 4 * h;
                f[j] = bf16_trunc(__expf(trans[r * NT + m]) * 0.0078125f);
            }
            Af[mt][kk] = f;
        }
    }

    // B := identity (in the permuted-B register convention)
    union BU { unsigned u[4]; bf16x8 v; };
    BU Bv[4][2];
#pragma unroll
    for (int kk = 0; kk < 4; ++kk)
#pragma unroll
        for (int nt = 0; nt < 2; ++nt) {
            int n = nt * 32 + ml;
#pragma unroll
            for (int d = 0; d < 4; ++d) {
                int j0 = 2 * d;
                int r0 = 32 * (kk >> 1) + 16 * (kk & 1) + (j0 & 3) + 8 * (j0 >> 2) + 4 * h;
                unsigned lo = (r0     == n) ? 0x3f80u : 0u;
                unsigned hi = (r0 + 1 == n) ? 0x3f80u : 0u;
                Bv[kk][nt].u[d] = lo | (hi << 16);
            }
        }

    __threadfence_block();  // w writes ordered before loop reads (same wave)

    const f32x16 zf = {};   // persistent zero C operand

    for (int s = 0; s < L; ++s) {
        // w quads for this step (broadcast reads, issued before MFMAs)
        const float* wrow = w_flat + s * NT;
        f32x4 wq[4][2];
#pragma unroll
        for (int kk = 0; kk < 4; ++kk) {
            int base = 32 * (kk >> 1) + 16 * (kk & 1) + 4 * h;
            wq[kk][0] = *(const f32x4*)(wrow + base);
            wq[kk][1] = *(const f32x4*)(wrow + base + 8);
        }

        // nt slices independent: process sequentially to halve live accs
#pragma unroll
        for (int nt = 0; nt < 2; ++nt) {
            __builtin_amdgcn_s_setprio(1);
            // layered K: consecutive MFMAs independent (dep distance 2)
            f32x16 a0 = __builtin_amdgcn_mfma_f32_32x32x16_bf16(Af[0][0], Bv[0][nt].v, zf, 0, 0, 0);
            f32x16 a1 = __builtin_amdgcn_mfma_f32_32x32x16_bf16(Af[1][0], Bv[0][nt].v, zf, 0, 0, 0);
#pragma unroll
            for (int kk = 1; kk < 4; ++kk) {
                a0 = __builtin_amdgcn_mfma_f32_32x32x16_bf16(Af[0][kk], Bv[kk][nt].v, a0, 0, 0, 0);
                a1 = __builtin_amdgcn_mfma_f32_32x32x16_bf16(Af[1][kk], Bv[kk][nt].v, a1, 0, 0, 0);
            }
            __builtin_amdgcn_s_setprio(0);

            // Rebuild B[:,nt] from row-scaled C: value (kk,h,j) = w[r]*C[r][n]
#pragma unroll
            for (int kk = 0; kk < 4; ++kk) {
                const int qo = 8 * (kk & 1);
                const f32x4 wa = wq[kk][0], wb = wq[kk][1];
#pragma unroll
                for (int d = 0; d < 4; ++d) {
                    const int j0 = 2 * d;
                    float w0 = (d < 2) ? wa[j0]     : wb[j0 - 4];
                    float w1 = (d < 2) ? wa[j0 + 1] : wb[j0 - 3];
                    f32x2 av, wv;
                    if (kk < 2) { av[0] = a0[qo + j0]; av[1] = a0[qo + j0 + 1]; }
                    else        { av[0] = a1[qo + j0]; av[1] = a1[qo + j0 + 1]; }
                    wv[0] = w0; wv[1] = w1;
                    f32x2 p = av * wv;          // v_pk_mul_f32
                    Bv[kk][nt].u[d] = pk_bf16(p[0], p[1]);
                }
            }
        }
    }

    // Transpose through LDS (once per chunk) -> mats[n][k] = M[k][n]
    __threadfence_block();
#pragma unroll
    for (int kk = 0; kk < 4; ++kk)
#pragma unroll
        for (int nt = 0; nt < 2; ++nt) {
            int n = nt * 32 + ml;
#pragma unroll
            for (int d = 0; d < 4; ++d) {
                int j0 = 2 * d;
                int r0 = 32 * (kk >> 1) + 16 * (kk & 1) + (j0 & 3) + 8 * (j0 >> 2) + 4 * h;
                *(unsigned*)&ldsT[n * PITCH + r0] = Bv[kk][nt].u[d];
            }
        }
    __threadfence_block();

    unsigned short* outp = mats + ((size_t)(b * PCH_ + c)) * 4096;
    for (int it = 0; it < 8; ++it) {
        int o = it * 512 + lane * 8;
        int n = o >> 6, k = o & 63;
        const uint2* p = (const uint2*)(ldsT + n * PITCH + k);
        uint2 x = p[0], y = p[1];
        uint4 q4; q4.x = x.x; q4.y = x.y; q4.z = y.x; q4.w = y.y;
        *(uint4*)(outp + o) = q4;
    }
}

// ---------------------------------------------------------------------------
// Packed chunk kernel: 4 waves per workgroup, each wave = one chunk chain on
// a private LDS slice. 1024 WGs = 4 WGs/CU -> 16 waves/CU guaranteed
// co-resident (sidesteps the observed ~8-WG/CU cap on 1-wave workgroups).
// No inter-wave synchronization: each wave's slice is private.
// ---------------------------------------------------------------------------
template<int PCH_, int CLEN_>
__global__ __launch_bounds__(256, 4) void crf_chunk_packed(
    const float* __restrict__ emissions,
    const float* __restrict__ trans,
    unsigned short* __restrict__ mats,
    float* __restrict__ ws_head)
{
    __shared__ __align__(16) unsigned char smem[4 * SLICE];

    const int tid  = threadIdx.x;
    const int lane = tid & 63;
    const int wave = tid >> 6;
    const int b    = blockIdx.y;
    const int c    = blockIdx.x * 4 + wave;

    if (blockIdx.x == 0 && b == 0 && tid == 0) {
        ws_head[0] = 0.f;
        ((unsigned*)ws_head)[1] = 0u;
    }

    chunk_wave<PCH_, CLEN_>(emissions, trans, mats, smem + wave * SLICE, b, c, lane);
}

// ---------------------------------------------------------------------------
// Single-wave chunk kernel (fallback paths only; R1-proven).
// ---------------------------------------------------------------------------
template<int PCH_, int CLEN_>
__global__ __launch_bounds__(64, 3) void crf_chunk_kernel(
    const float* __restrict__ emissions,
    const float* __restrict__ trans,
    unsigned short* __restrict__ mats,
    float* __restrict__ ws_head)
{
    constexpr int SMEM = (CLEN_ * NT * 4 > 64 * PITCH * 2) ? CLEN_ * NT * 4 : 64 * PITCH * 2;
    __shared__ __align__(16) unsigned char smem[SMEM];

    const int c    = blockIdx.x;
    const int b    = blockIdx.y;
    const int lane = threadIdx.x;

    if (c == 0 && b == 0 && lane == 0) {
        ws_head[0] = 0.f;
        ((unsigned*)ws_head)[1] = 0u;
    }

    chunk_wave<PCH_, CLEN_>(emissions, trans, mats, smem, b, c, lane);
}

// ---------------------------------------------------------------------------
// Combine: 1 block/batch, 4 waves. Wave 0: PCH-step matvec chain (register
// double-buffered). Wave 1: gold-path numerator. Waves 2-3: L2 prefetch of
// this batch's chunk matrices. Final mean via device-scope atomics.
// ---------------------------------------------------------------------------
template<int PCH_>
__global__ __launch_bounds__(256) void crf_combine_kernel(
    const float* __restrict__ emissions,
    const int*   __restrict__ tags,
    const int*   __restrict__ mask,
    const float* __restrict__ start_tr,
    const float* __restrict__ end_tr,
    const float* __restrict__ trans,
    const unsigned short* __restrict__ mats,
    float* __restrict__ ws_head,
    float* __restrict__ out)
{
    __shared__ __align__(16) float r_lds[NT];
    __shared__ float score_lds;

    const int b    = blockIdx.x;
    const int tid  = threadIdx.x;
    const int j    = tid & 63;
    const int wave = tid >> 6;

    const float* em_b = emissions + (size_t)b * SEQ * NT;
    const int*   tg_b = tags + b * SEQ;
    const int*   mk_b = mask + b * SEQ;
    const unsigned short* mb = mats + (size_t)b * PCH_ * 4096;

    float denom = 0.f;

    if (wave >= 2) {
        // touch all of this batch's mats lines (PCH_*512 uint4s)
        const uint4* p = (const uint4*)mb;
        unsigned acc = 0;
        for (int i = (wave - 2) * 64 + j; i < PCH_ * 512; i += 128) {
            uint4 q = p[i];
            acc += q.x + q.y + q.z + q.w;
        }
        if (acc == 0xdeadbeefu) ws_head[2] = -1.f;  // keep loads alive (harmless)
    } else if (wave == 1) {
        // ---------------- numerator (gold-path score) ----------------
        float part = 0.f;
        int mcount = 0;
        for (int s = j; s < SEQ; s += 64) {
            int m = mk_b[s];
            mcount += m;
            int t = tg_b[s];
            if (s == 0) {
                part += start_tr[t] + em_b[t];
            } else {
                int tp = tg_b[s - 1];
                float v = trans[tp * NT + t] + em_b[s * NT + t];
                part += m ? v : 0.f;
            }
        }
#pragma unroll
        for (int d = 32; d; d >>= 1) {
            part   += __shfl_xor(part, d);
            mcount += __shfl_xor(mcount, d);
        }
        if (j == 0) score_lds = part + end_tr[tg_b[mcount - 1]];
    } else {
        // ---------------- chain: r^T <- r^T M_c, c = PCH_-1..0 ----------------
        float r = __expf(end_tr[j]);
        r_lds[j] = r;
        __threadfence_block();
        int X = 0;

        uint4 cur[8], nxt[8];
#pragma unroll
        for (int u = 0; u < 8; ++u)
            cur[u] = *(const uint4*)(mb + (size_t)(PCH_ - 1) * 4096 + j * 64 + u * 8);

        for (int c = PCH_ - 1; c >= 0; --c) {
            if (c > 0) {
#pragma unroll
                for (int u = 0; u < 8; ++u)
                    nxt[u] = *(const uint4*)(mb + (size_t)(c - 1) * 4096 + j * 64 + u * 8);
            }
            float a0 = 0.f, a1 = 0.f, a2 = 0.f, a3 = 0.f;
#pragma unroll
            for (int u = 0; u < 8; ++u) {
                uint4 q = cur[u];
                f32x4 ra = *(const f32x4*)&r_lds[u * 8];
                f32x4 rb = *(const f32x4*)&r_lds[u * 8 + 4];
                a0 = fmaf(ra[0], __uint_as_float(q.x << 16),         a0);
                a1 = fmaf(ra[1], __uint_as_float(q.x & 0xffff0000u), a1);
                a2 = fmaf(ra[2], __uint_as_float(q.y << 16),         a2);
                a3 = fmaf(ra[3], __uint_as_float(q.y & 0xffff0000u), a3);
                a0 = fmaf(rb[0], __uint_as_float(q.z << 16),         a0);
                a1 = fmaf(rb[1], __uint_as_float(q.z & 0xffff0000u), a1);
                a2 = fmaf(rb[2], __uint_as_float(q.w << 16),         a2);
                a3 = fmaf(rb[3], __uint_as_float(q.w & 0xffff0000u), a3);
            }
            float rn = (a0 + a1) + (a2 + a3);
            unsigned eb = (__builtin_amdgcn_readfirstlane((int)__float_as_uint(rn)) >> 23) & 0xffu;
            r = rn * __uint_as_float((254u - eb) << 23);   // * 2^(127-eb)
            X += (int)eb - 127;
            r_lds[j] = r;
            __threadfence_block();
#pragma unroll
            for (int u = 0; u < 8; ++u) cur[u] = nxt[u];
        }

        float u0 = __expf(start_tr[j] + em_b[j]);
        float v = r * u0;
#pragma unroll
        for (int d = 32; d; d >>= 1) v += __shfl_xor(v, d);
        denom = __logf(v) + (float)(X + 7 * (SEQ - 1)) * 0.6931471805599453f;
    }

    __syncthreads();  // score_lds ready

    if (wave == 0 && j == 0) {
        float llh = denom - score_lds;
        atomicAdd(&ws_head[0], llh * (1.0f / BATCH));
        __threadfence();
        unsigned old = atomicAdd((unsigned*)ws_head + 1, 1u);
        if (old == BATCH - 1) {
            __threadfence();
            out[0] = atomicAdd(&ws_head[0], 0.0f);  // coherent read of final sum
        }
    }
}

extern "C" void kernel_launch(void* const* d_in, const int* in_sizes, int n_in,
                              void* d_out, int out_size, void* d_ws, size_t ws_size,
                              hipStream_t stream) {
    const float* emissions = (const float*)d_in[0];
    const int*   tags      = (const int*)d_in[1];
    const int*   mask      = (const int*)d_in[2];
    const float* start_tr  = (const float*)d_in[3];
    const float* end_tr    = (const float*)d_in[4];
    const float* trans     = (const float*)d_in[5];

    float* ws_head = (float*)d_ws;                                 // sum/cnt/dummy
    unsigned short* mats = (unsigned short*)((char*)d_ws + 4096);  // bf16 chunk mats

    const size_t need16 = 4096 + (size_t)BATCH * 16 * 4096 * sizeof(unsigned short);
    const size_t need12 = 4096 + (size_t)BATCH * 12 * 4096 * sizeof(unsigned short);
    if (ws_size >= need16) {
        // PCH=16, CLEN=32, 4 chains per 256-thread WG: 1024 WGs = 4 WGs/CU
        // = 16 waves/CU guaranteed co-resident.
        crf_chunk_packed<16, 32><<<dim3(4, BATCH), 256, 0, stream>>>(emissions, trans, mats, ws_head);
        crf_combine_kernel<16><<<BATCH, 256, 0, stream>>>(emissions, tags, mask,
                                                          start_tr, end_tr, trans, mats,
                                                          ws_head, (float*)d_out);
    } else if (ws_size >= need12) {
        // PCH=12, CLEN=43: proven round-1 configuration
        crf_chunk_kernel<12, 43><<<dim3(12, BATCH), 64, 0, stream>>>(emissions, trans, mats, ws_head);
        crf_combine_kernel<12><<<BATCH, 256, 0, stream>>>(emissions, tags, mask,
                                                          start_tr, end_tr, trans, mats,
                                                          ws_head, (float*)d_out);
    } else {
        // fallback: PCH=8 footprint (16.8 MB)
        crf_chunk_kernel<8, 64><<<dim3(8, BATCH), 64, 0, stream>>>(emissions, trans, mats, ws_head);
        crf_combine_kernel<8><<<BATCH, 256, 0, stream>>>(emissions, tags, mask,
                                                         start_tr, end_tr, trans, mats,
                                                         ws_head, (float*)d_out);
    }
}

// Round 6
// 151.032 us; speedup vs baseline: 1.6619x; 1.6619x over previous
//
#include <hip/hip_runtime.h>

#define BATCH 256
#define SEQ   512
#define NT    64
#define PITCH 68    // ldsT pitch in halves (final transpose only)

typedef __attribute__((ext_vector_type(8)))  short bf16x8;
typedef __attribute__((ext_vector_type(16))) float f32x16;
typedef __attribute__((ext_vector_type(4)))  float f32x4;
typedef __attribute__((ext_vector_type(2)))  float f32x2;

static __device__ __forceinline__ unsigned pk_bf16(float lo, float hi) {
    // dst = lo.bf16 | (hi.bf16 << 16), truncation — single v_perm_b32
    return __builtin_amdgcn_perm(__float_as_uint(hi), __float_as_uint(lo), 0x07060302u);
}
static __device__ __forceinline__ short bf16_trunc(float v) {
    return (short)(__float_as_uint(v) >> 16);
}

// per-wave LDS slice bytes for a given CLEN (16B aligned)
template<int CLEN_>
struct slice_bytes {
    static constexpr int v = (CLEN_ * NT * 4 > 64 * PITCH * 2) ? CLEN_ * NT * 4 : 64 * PITCH * 2;
};

// ---------------------------------------------------------------------------
// Core per-wave chunk routine (R1-proven inner loop, verbatim).
// One wave owns one (batch, chunk) chain on a private LDS slice.
// ---------------------------------------------------------------------------
template<int PCH_, int CLEN_>
static __device__ __forceinline__ void chunk_wave(
    const float* __restrict__ emissions,
    const float* __restrict__ trans,
    unsigned short* __restrict__ mats,
    unsigned char* slice,          // slice_bytes<CLEN_>, 16B aligned, wave-private
    int b, int c, int lane)
{
    float*          w_flat = (float*)slice;
    unsigned short* ldsT   = (unsigned short*)slice;

    const int h  = lane >> 5;
    const int ml = lane & 31;

    const int s0 = c * CLEN_;
    int L = (SEQ - 1) - s0; if (L > CLEN_) L = CLEN_;

    const float* em_b = emissions + (size_t)b * SEQ * NT;

    // ---- staging: w = exp(em) for steps s0+1 .. s0+L, vectorized float4 ----
    {
        const float4* src = (const float4*)(em_b + (size_t)(s0 + 1) * NT);
        float4*       dst = (float4*)w_flat;
        const int total4 = L * (NT / 4);
        for (int i = lane; i < total4; i += 64) {
            float4 v = src[i];
            v.x = __expf(v.x); v.y = __expf(v.y);
            v.z = __expf(v.z); v.w = __expf(v.w);
            dst[i] = v;
        }
    }

    // Permuted A: Af[mt][kk] slot (h,j) = Es[mt*32+ml][r], Es = E^T * 2^-7,
    // r = 32*(kk>>1) + 16*(kk&1) + (j&3) + 8*(j>>2) + 4h
    bf16x8 Af[2][4];
#pragma unroll
    for (int mt = 0; mt < 2; ++mt) {
        int m = mt * 32 + ml;
#pragma unroll
        for (int kk = 0; kk < 4; ++kk) {
            bf16x8 f;
#pragma unroll
            for (int j = 0; j < 8; ++j) {
                int r = 32 * (kk >> 1) + 16 * (kk & 1) + (j & 3) + 8 * (j >> 2) + 4 * h;
                f[j] = bf16_trunc(__expf(trans[r * NT + m]) * 0.0078125f);
            }
            Af[mt][kk] = f;
        }
    }

    // B := identity (in the permuted-B register convention)
    union BU { unsigned u[4]; bf16x8 v; };
    BU Bv[4][2];
#pragma unroll
    for (int kk = 0; kk < 4; ++kk)
#pragma unroll
        for (int nt = 0; nt < 2; ++nt) {
            int n = nt * 32 + ml;
#pragma unroll
            for (int d = 0; d < 4; ++d) {
                int j0 = 2 * d;
                int r0 = 32 * (kk >> 1) + 16 * (kk & 1) + (j0 & 3) + 8 * (j0 >> 2) + 4 * h;
                unsigned lo = (r0     == n) ? 0x3f80u : 0u;
                unsigned hi = (r0 + 1 == n) ? 0x3f80u : 0u;
                Bv[kk][nt].u[d] = lo | (hi << 16);
            }
        }

    __threadfence_block();  // w writes ordered before loop reads (same wave)

    const f32x16 zf = {};   // persistent zero C operand

    for (int s = 0; s < L; ++s) {
        // w quads for this step (broadcast reads, issued before MFMAs)
        const float* wrow = w_flat + s * NT;
        f32x4 wq[4][2];
#pragma unroll
        for (int kk = 0; kk < 4; ++kk) {
            int base = 32 * (kk >> 1) + 16 * (kk & 1) + 4 * h;
            wq[kk][0] = *(const f32x4*)(wrow + base);
            wq[kk][1] = *(const f32x4*)(wrow + base + 8);
        }

        // nt slices independent: process sequentially to halve live accs
#pragma unroll
        for (int nt = 0; nt < 2; ++nt) {
            __builtin_amdgcn_s_setprio(1);
            // layered K: consecutive MFMAs independent (dep distance 2)
            f32x16 a0 = __builtin_amdgcn_mfma_f32_32x32x16_bf16(Af[0][0], Bv[0][nt].v, zf, 0, 0, 0);
            f32x16 a1 = __builtin_amdgcn_mfma_f32_32x32x16_bf16(Af[1][0], Bv[0][nt].v, zf, 0, 0, 0);
#pragma unroll
            for (int kk = 1; kk < 4; ++kk) {
                a0 = __builtin_amdgcn_mfma_f32_32x32x16_bf16(Af[0][kk], Bv[kk][nt].v, a0, 0, 0, 0);
                a1 = __builtin_amdgcn_mfma_f32_32x32x16_bf16(Af[1][kk], Bv[kk][nt].v, a1, 0, 0, 0);
            }
            __builtin_amdgcn_s_setprio(0);

            // Rebuild B[:,nt] from row-scaled C: value (kk,h,j) = w[r]*C[r][n]
#pragma unroll
            for (int kk = 0; kk < 4; ++kk) {
                const int qo = 8 * (kk & 1);
                const f32x4 wa = wq[kk][0], wb = wq[kk][1];
#pragma unroll
                for (int d = 0; d < 4; ++d) {
                    const int j0 = 2 * d;
                    float w0 = (d < 2) ? wa[j0]     : wb[j0 - 4];
                    float w1 = (d < 2) ? wa[j0 + 1] : wb[j0 - 3];
                    f32x2 av, wv;
                    if (kk < 2) { av[0] = a0[qo + j0]; av[1] = a0[qo + j0 + 1]; }
                    else        { av[0] = a1[qo + j0]; av[1] = a1[qo + j0 + 1]; }
                    wv[0] = w0; wv[1] = w1;
                    f32x2 p = av * wv;          // v_pk_mul_f32
                    Bv[kk][nt].u[d] = pk_bf16(p[0], p[1]);
                }
            }
        }
    }

    // Transpose through LDS (once per chunk) -> mats[n][k] = M[k][n]
    __threadfence_block();
#pragma unroll
    for (int kk = 0; kk < 4; ++kk)
#pragma unroll
        for (int nt = 0; nt < 2; ++nt) {
            int n = nt * 32 + ml;
#pragma unroll
            for (int d = 0; d < 4; ++d) {
                int j0 = 2 * d;
                int r0 = 32 * (kk >> 1) + 16 * (kk & 1) + (j0 & 3) + 8 * (j0 >> 2) + 4 * h;
                *(unsigned*)&ldsT[n * PITCH + r0] = Bv[kk][nt].u[d];
            }
        }
    __threadfence_block();

    unsigned short* outp = mats + ((size_t)(b * PCH_ + c)) * 4096;
    for (int it = 0; it < 8; ++it) {
        int o = it * 512 + lane * 8;
        int n = o >> 6, k = o & 63;
        const uint2* p = (const uint2*)(ldsT + n * PITCH + k);
        uint2 x = p[0], y = p[1];
        uint4 q4; q4.x = x.x; q4.y = x.y; q4.z = y.x; q4.w = y.y;
        *(uint4*)(outp + o) = q4;
    }
}

// ---------------------------------------------------------------------------
// Packed chunk kernel: 4 waves per workgroup, each wave = one chunk chain on
// a private LDS slice. R5 lesson: packing DOES lift residency past the
// ~8-WG/CU cap on 1-wave WGs (occ 24->36%), but launch_bounds(256,4)'s
// 128-reg budget spilled (~132-reg working set) -> 65 MB scratch traffic.
// This round: (256,3) keeps the proven spill-free 170-reg budget; grid
// 3 WGs/CU exactly (768 WGs) -> 12 waves/CU co-resident, no tail.
// ---------------------------------------------------------------------------
template<int PCH_, int CLEN_>
__global__ __launch_bounds__(256, 3) void crf_chunk_packed(
    const float* __restrict__ emissions,
    const float* __restrict__ trans,
    unsigned short* __restrict__ mats,
    float* __restrict__ ws_head)
{
    constexpr int SLICE_B = slice_bytes<CLEN_>::v;
    __shared__ __align__(16) unsigned char smem[4 * SLICE_B];

    const int tid  = threadIdx.x;
    const int lane = tid & 63;
    const int wave = tid >> 6;
    const int b    = blockIdx.y;
    const int c    = blockIdx.x * 4 + wave;

    if (blockIdx.x == 0 && b == 0 && tid == 0) {
        ws_head[0] = 0.f;
        ((unsigned*)ws_head)[1] = 0u;
    }

    chunk_wave<PCH_, CLEN_>(emissions, trans, mats, smem + wave * SLICE_B, b, c, lane);
}

// ---------------------------------------------------------------------------
// Single-wave chunk kernel (fallback path only; R1-proven).
// ---------------------------------------------------------------------------
template<int PCH_, int CLEN_>
__global__ __launch_bounds__(64, 3) void crf_chunk_kernel(
    const float* __restrict__ emissions,
    const float* __restrict__ trans,
    unsigned short* __restrict__ mats,
    float* __restrict__ ws_head)
{
    constexpr int SMEM = slice_bytes<CLEN_>::v;
    __shared__ __align__(16) unsigned char smem[SMEM];

    const int c    = blockIdx.x;
    const int b    = blockIdx.y;
    const int lane = threadIdx.x;

    if (c == 0 && b == 0 && lane == 0) {
        ws_head[0] = 0.f;
        ((unsigned*)ws_head)[1] = 0u;
    }

    chunk_wave<PCH_, CLEN_>(emissions, trans, mats, smem, b, c, lane);
}

// ---------------------------------------------------------------------------
// Combine: 1 block/batch, 4 waves. Wave 0: PCH-step matvec chain (register
// double-buffered). Wave 1: gold-path numerator. Waves 2-3: L2 prefetch of
// this batch's chunk matrices. Final mean via device-scope atomics.
// ---------------------------------------------------------------------------
template<int PCH_>
__global__ __launch_bounds__(256) void crf_combine_kernel(
    const float* __restrict__ emissions,
    const int*   __restrict__ tags,
    const int*   __restrict__ mask,
    const float* __restrict__ start_tr,
    const float* __restrict__ end_tr,
    const float* __restrict__ trans,
    const unsigned short* __restrict__ mats,
    float* __restrict__ ws_head,
    float* __restrict__ out)
{
    __shared__ __align__(16) float r_lds[NT];
    __shared__ float score_lds;

    const int b    = blockIdx.x;
    const int tid  = threadIdx.x;
    const int j    = tid & 63;
    const int wave = tid >> 6;

    const float* em_b = emissions + (size_t)b * SEQ * NT;
    const int*   tg_b = tags + b * SEQ;
    const int*   mk_b = mask + b * SEQ;
    const unsigned short* mb = mats + (size_t)b * PCH_ * 4096;

    float denom = 0.f;

    if (wave >= 2) {
        // touch all of this batch's mats lines (PCH_*512 uint4s)
        const uint4* p = (const uint4*)mb;
        unsigned acc = 0;
        for (int i = (wave - 2) * 64 + j; i < PCH_ * 512; i += 128) {
            uint4 q = p[i];
            acc += q.x + q.y + q.z + q.w;
        }
        if (acc == 0xdeadbeefu) ws_head[2] = -1.f;  // keep loads alive (harmless)
    } else if (wave == 1) {
        // ---------------- numerator (gold-path score) ----------------
        float part = 0.f;
        int mcount = 0;
        for (int s = j; s < SEQ; s += 64) {
            int m = mk_b[s];
            mcount += m;
            int t = tg_b[s];
            if (s == 0) {
                part += start_tr[t] + em_b[t];
            } else {
                int tp = tg_b[s - 1];
                float v = trans[tp * NT + t] + em_b[s * NT + t];
                part += m ? v : 0.f;
            }
        }
#pragma unroll
        for (int d = 32; d; d >>= 1) {
            part   += __shfl_xor(part, d);
            mcount += __shfl_xor(mcount, d);
        }
        if (j == 0) score_lds = part + end_tr[tg_b[mcount - 1]];
    } else {
        // ---------------- chain: r^T <- r^T M_c, c = PCH_-1..0 ----------------
        float r = __expf(end_tr[j]);
        r_lds[j] = r;
        __threadfence_block();
        int X = 0;

        uint4 cur[8], nxt[8];
#pragma unroll
        for (int u = 0; u < 8; ++u)
            cur[u] = *(const uint4*)(mb + (size_t)(PCH_ - 1) * 4096 + j * 64 + u * 8);

        for (int c = PCH_ - 1; c >= 0; --c) {
            if (c > 0) {
#pragma unroll
                for (int u = 0; u < 8; ++u)
                    nxt[u] = *(const uint4*)(mb + (size_t)(c - 1) * 4096 + j * 64 + u * 8);
            }
            float a0 = 0.f, a1 = 0.f, a2 = 0.f, a3 = 0.f;
#pragma unroll
            for (int u = 0; u < 8; ++u) {
                uint4 q = cur[u];
                f32x4 ra = *(const f32x4*)&r_lds[u * 8];
                f32x4 rb = *(const f32x4*)&r_lds[u * 8 + 4];
                a0 = fmaf(ra[0], __uint_as_float(q.x << 16),         a0);
                a1 = fmaf(ra[1], __uint_as_float(q.x & 0xffff0000u), a1);
                a2 = fmaf(ra[2], __uint_as_float(q.y << 16),         a2);
                a3 = fmaf(ra[3], __uint_as_float(q.y & 0xffff0000u), a3);
                a0 = fmaf(rb[0], __uint_as_float(q.z << 16),         a0);
                a1 = fmaf(rb[1], __uint_as_float(q.z & 0xffff0000u), a1);
                a2 = fmaf(rb[2], __uint_as_float(q.w << 16),         a2);
                a3 = fmaf(rb[3], __uint_as_float(q.w & 0xffff0000u), a3);
            }
            float rn = (a0 + a1) + (a2 + a3);
            unsigned eb = (__builtin_amdgcn_readfirstlane((int)__float_as_uint(rn)) >> 23) & 0xffu;
            r = rn * __uint_as_float((254u - eb) << 23);   // * 2^(127-eb)
            X += (int)eb - 127;
            r_lds[j] = r;
            __threadfence_block();
#pragma unroll
            for (int u = 0; u < 8; ++u) cur[u] = nxt[u];
        }

        float u0 = __expf(start_tr[j] + em_b[j]);
        float v = r * u0;
#pragma unroll
        for (int d = 32; d; d >>= 1) v += __shfl_xor(v, d);
        denom = __logf(v) + (float)(X + 7 * (SEQ - 1)) * 0.6931471805599453f;
    }

    __syncthreads();  // score_lds ready

    if (wave == 0 && j == 0) {
        float llh = denom - score_lds;
        atomicAdd(&ws_head[0], llh * (1.0f / BATCH));
        __threadfence();
        unsigned old = atomicAdd((unsigned*)ws_head + 1, 1u);
        if (old == BATCH - 1) {
            __threadfence();
            out[0] = atomicAdd(&ws_head[0], 0.0f);  // coherent read of final sum
        }
    }
}

extern "C" void kernel_launch(void* const* d_in, const int* in_sizes, int n_in,
                              void* d_out, int out_size, void* d_ws, size_t ws_size,
                              hipStream_t stream) {
    const float* emissions = (const float*)d_in[0];
    const int*   tags      = (const int*)d_in[1];
    const int*   mask      = (const int*)d_in[2];
    const float* start_tr  = (const float*)d_in[3];
    const float* end_tr    = (const float*)d_in[4];
    const float* trans     = (const float*)d_in[5];

    float* ws_head = (float*)d_ws;                                 // sum/cnt/dummy
    unsigned short* mats = (unsigned short*)((char*)d_ws + 4096);  // bf16 chunk mats

    const size_t need12 = 4096 + (size_t)BATCH * 12 * 4096 * sizeof(unsigned short);
    if (ws_size >= need12) {
        // PCH=12, CLEN=43, 4 chains per 256-thread WG: 768 WGs = exactly
        // 3 WGs/CU co-resident (LDS 3x44KB=132KB, regs 170-budget) ->
        // 12 waves/CU uniformly, no spills, no tail.
        crf_chunk_packed<12, 43><<<dim3(3, BATCH), 256, 0, stream>>>(emissions, trans, mats, ws_head);
        crf_combine_kernel<12><<<BATCH, 256, 0, stream>>>(emissions, tags, mask,
                                                          start_tr, end_tr, trans, mats,
                                                          ws_head, (float*)d_out);
    } else {
        // fallback: PCH=8 single-wave footprint (16.8 MB)
        crf_chunk_kernel<8, 64><<<dim3(8, BATCH), 64, 0, stream>>>(emissions, trans, mats, ws_head);
        crf_combine_kernel<8><<<BATCH, 256, 0, stream>>>(emissions, tags, mask,
                                                         start_tr, end_tr, trans, mats,
                                                         ws_head, (float*)d_out);
    }
}

// Round 7
// 150.431 us; speedup vs baseline: 1.6685x; 1.0040x over previous
//
#include <hip/hip_runtime.h>

#define BATCH 256
#define SEQ   512
#define NT    64
#define PITCH 68    // ldsT pitch in halves (final transpose only)

typedef __attribute__((ext_vector_type(8)))  short bf16x8;
typedef __attribute__((ext_vector_type(16))) float f32x16;
typedef __attribute__((ext_vector_type(4)))  float f32x4;
typedef __attribute__((ext_vector_type(2)))  float f32x2;

static __device__ __forceinline__ unsigned pk_bf16(float lo, float hi) {
    // dst = lo.bf16 | (hi.bf16 << 16), truncation — single v_perm_b32
    return __builtin_amdgcn_perm(__float_as_uint(hi), __float_as_uint(lo), 0x07060302u);
}
static __device__ __forceinline__ short bf16_trunc(float v) {
    return (short)(__float_as_uint(v) >> 16);
}

// per-chunk LDS slice bytes (w staging region; ldsT overlays it post-loop)
template<int CLEN_>
struct slice_bytes {
    static constexpr int v = (CLEN_ * NT * 4 > 64 * PITCH * 2) ? CLEN_ * NT * 4 : 64 * PITCH * 2;
};

// ---------------------------------------------------------------------------
// Column-split chunk wave: one wave owns ONE column half (nt fixed) of one
// (batch, chunk) chain. B-columns are independent across the chain, so the
// two waves of a chunk never communicate except via the shared read-only w
// staging (barrier-protected). Per-wave register state ~124 unified
// (Af 32 + Bv 16 + acc 32 + wq 32 + addr) -> fits the <=128 bucket ->
// 4 waves/SIMD resident (R5 proved the bucket; R5 spilled because its
// full-width working set was ~132; this one genuinely fits).
// ---------------------------------------------------------------------------
template<int PCH_, int CLEN_>
static __device__ __forceinline__ void chunk_wave_half(
    const float* __restrict__ emissions,
    const float* __restrict__ trans,
    unsigned short* __restrict__ mats,
    unsigned char* slice,          // per-chunk slice, shared by its 2 waves
    int b, int c, int nt, int lane)
{
    float*          w_flat = (float*)slice;
    unsigned short* ldsT   = (unsigned short*)slice;

    const int h  = lane >> 5;
    const int ml = lane & 31;

    const int s0 = c * CLEN_;
    int L = (SEQ - 1) - s0; if (L > CLEN_) L = CLEN_;

    const float* em_b = emissions + (size_t)b * SEQ * NT;

    // ---- staging: w = exp(em), cooperatively by the chunk's 2 waves ----
    {
        const float4* src = (const float4*)(em_b + (size_t)(s0 + 1) * NT);
        float4*       dst = (float4*)w_flat;
        const int total4 = L * (NT / 4);
        for (int i = nt * 64 + lane; i < total4; i += 128) {
            float4 v = src[i];
            v.x = __expf(v.x); v.y = __expf(v.y);
            v.z = __expf(v.z); v.w = __expf(v.w);
            dst[i] = v;
        }
    }

    // Permuted A: Af[mt][kk] slot (h,j) = Es[mt*32+ml][r], Es = E^T * 2^-7,
    // r = 32*(kk>>1) + 16*(kk&1) + (j&3) + 8*(j>>2) + 4h
    bf16x8 Af[2][4];
#pragma unroll
    for (int mt = 0; mt < 2; ++mt) {
        int m = mt * 32 + ml;
#pragma unroll
        for (int kk = 0; kk < 4; ++kk) {
            bf16x8 f;
#pragma unroll
            for (int j = 0; j < 8; ++j) {
                int r = 32 * (kk >> 1) + 16 * (kk & 1) + (j & 3) + 8 * (j >> 2) + 4 * h;
                f[j] = bf16_trunc(__expf(trans[r * NT + m]) * 0.0078125f);
            }
            Af[mt][kk] = f;
        }
    }

    // B := identity columns for this wave's half (n = nt*32+ml)
    union BU { unsigned u[4]; bf16x8 v; };
    BU Bv[4];
    {
        int n = nt * 32 + ml;
#pragma unroll
        for (int kk = 0; kk < 4; ++kk)
#pragma unroll
            for (int d = 0; d < 4; ++d) {
                int j0 = 2 * d;
                int r0 = 32 * (kk >> 1) + 16 * (kk & 1) + (j0 & 3) + 8 * (j0 >> 2) + 4 * h;
                unsigned lo = (r0     == n) ? 0x3f80u : 0u;
                unsigned hi = (r0 + 1 == n) ? 0x3f80u : 0u;
                Bv[kk].u[d] = lo | (hi << 16);
            }
    }

    __syncthreads();   // staging complete (both waves) before loop reads

    const f32x16 zf = {};   // zero C operand (allocator may rematerialize)

    for (int s = 0; s < L; ++s) {
        // w quads for this step (broadcast reads, issued before MFMAs)
        const float* wrow = w_flat + s * NT;
        f32x4 wq[4][2];
#pragma unroll
        for (int kk = 0; kk < 4; ++kk) {
            int base = 32 * (kk >> 1) + 16 * (kk & 1) + 4 * h;
            wq[kk][0] = *(const f32x4*)(wrow + base);
            wq[kk][1] = *(const f32x4*)(wrow + base + 8);
        }

        __builtin_amdgcn_s_setprio(1);
        // two independent 4-deep K chains (rows 0-31 and 32-63)
        f32x16 a0 = __builtin_amdgcn_mfma_f32_32x32x16_bf16(Af[0][0], Bv[0].v, zf, 0, 0, 0);
        f32x16 a1 = __builtin_amdgcn_mfma_f32_32x32x16_bf16(Af[1][0], Bv[0].v, zf, 0, 0, 0);
#pragma unroll
        for (int kk = 1; kk < 4; ++kk) {
            a0 = __builtin_amdgcn_mfma_f32_32x32x16_bf16(Af[0][kk], Bv[kk].v, a0, 0, 0, 0);
            a1 = __builtin_amdgcn_mfma_f32_32x32x16_bf16(Af[1][kk], Bv[kk].v, a1, 0, 0, 0);
        }
        __builtin_amdgcn_s_setprio(0);

        // Rebuild B from row-scaled C: value (kk,h,j) = w[r]*C[r][n]
#pragma unroll
        for (int kk = 0; kk < 4; ++kk) {
            const int qo = 8 * (kk & 1);
            const f32x4 wa = wq[kk][0], wb = wq[kk][1];
#pragma unroll
            for (int d = 0; d < 4; ++d) {
                const int j0 = 2 * d;
                float w0 = (d < 2) ? wa[j0]     : wb[j0 - 4];
                float w1 = (d < 2) ? wa[j0 + 1] : wb[j0 - 3];
                f32x2 av, wv;
                if (kk < 2) { av[0] = a0[qo + j0]; av[1] = a0[qo + j0 + 1]; }
                else        { av[0] = a1[qo + j0]; av[1] = a1[qo + j0 + 1]; }
                wv[0] = w0; wv[1] = w1;
                f32x2 p = av * wv;          // v_pk_mul_f32
                Bv[kk].u[d] = pk_bf16(p[0], p[1]);
            }
        }
    }

    // Transpose through LDS (ldsT overlays w; barrier: other wave may still
    // be reading w until it finishes its loop)
    __syncthreads();
    {
        int n = nt * 32 + ml;
#pragma unroll
        for (int kk = 0; kk < 4; ++kk)
#pragma unroll
            for (int d = 0; d < 4; ++d) {
                int j0 = 2 * d;
                int r0 = 32 * (kk >> 1) + 16 * (kk & 1) + (j0 & 3) + 8 * (j0 >> 2) + 4 * h;
                *(unsigned*)&ldsT[n * PITCH + r0] = Bv[kk].u[d];
            }
    }
    __threadfence_block();   // own writes visible to own reads below

    // Write out own rows n in [nt*32, nt*32+32): 32 rows x 128B = 4KB
    unsigned short* outp = mats + ((size_t)(b * PCH_ + c)) * 4096;
    for (int it = 0; it < 4; ++it) {
        int o = nt * 2048 + it * 512 + lane * 8;
        int n = o >> 6, k = o & 63;
        const uint2* p = (const uint2*)(ldsT + n * PITCH + k);
        uint2 x = p[0], y = p[1];
        uint4 q4; q4.x = x.x; q4.y = x.y; q4.z = y.x; q4.w = y.y;
        *(uint4*)(outp + o) = q4;
    }
}

// ---------------------------------------------------------------------------
// Split chunk kernel: 4 waves per WG = 2 chunks x 2 column-halves.
// PCH=8 -> grid 4 x 256 = 1024 WGs = 4 WGs/CU = 16 waves/CU co-resident
// (LDS 4 x 32KB = 128KB <= 160KB; regs <=128 via launch_bounds(256,4)).
// ---------------------------------------------------------------------------
template<int PCH_, int CLEN_>
__global__ __launch_bounds__(256, 4) void crf_chunk_split(
    const float* __restrict__ emissions,
    const float* __restrict__ trans,
    unsigned short* __restrict__ mats,
    float* __restrict__ ws_head)
{
    constexpr int SLICE_CH = slice_bytes<CLEN_>::v;
    __shared__ __align__(16) unsigned char smem[2 * SLICE_CH];

    const int tid  = threadIdx.x;
    const int lane = tid & 63;
    const int w    = tid >> 6;
    const int b    = blockIdx.y;
    const int c    = blockIdx.x * 2 + (w >> 1);
    const int nt   = w & 1;

    if (blockIdx.x == 0 && b == 0 && tid == 0) {
        ws_head[0] = 0.f;
        ((unsigned*)ws_head)[1] = 0u;
    }

    chunk_wave_half<PCH_, CLEN_>(emissions, trans, mats,
                                 smem + (w >> 1) * SLICE_CH, b, c, nt, lane);
}

// ---------------------------------------------------------------------------
// Combine: 1 block/batch, 4 waves. Wave 0: PCH-step matvec chain (register
// double-buffered). Wave 1: gold-path numerator. Waves 2-3: L2 prefetch of
// this batch's chunk matrices. Final mean via device-scope atomics.
// ---------------------------------------------------------------------------
template<int PCH_>
__global__ __launch_bounds__(256) void crf_combine_kernel(
    const float* __restrict__ emissions,
    const int*   __restrict__ tags,
    const int*   __restrict__ mask,
    const float* __restrict__ start_tr,
    const float* __restrict__ end_tr,
    const float* __restrict__ trans,
    const unsigned short* __restrict__ mats,
    float* __restrict__ ws_head,
    float* __restrict__ out)
{
    __shared__ __align__(16) float r_lds[NT];
    __shared__ float score_lds;

    const int b    = blockIdx.x;
    const int tid  = threadIdx.x;
    const int j    = tid & 63;
    const int wave = tid >> 6;

    const float* em_b = emissions + (size_t)b * SEQ * NT;
    const int*   tg_b = tags + b * SEQ;
    const int*   mk_b = mask + b * SEQ;
    const unsigned short* mb = mats + (size_t)b * PCH_ * 4096;

    float denom = 0.f;

    if (wave >= 2) {
        // touch all of this batch's mats lines (PCH_*512 uint4s)
        const uint4* p = (const uint4*)mb;
        unsigned acc = 0;
        for (int i = (wave - 2) * 64 + j; i < PCH_ * 512; i += 128) {
            uint4 q = p[i];
            acc += q.x + q.y + q.z + q.w;
        }
        if (acc == 0xdeadbeefu) ws_head[2] = -1.f;  // keep loads alive (harmless)
    } else if (wave == 1) {
        // ---------------- numerator (gold-path score) ----------------
        float part = 0.f;
        int mcount = 0;
        for (int s = j; s < SEQ; s += 64) {
            int m = mk_b[s];
            mcount += m;
            int t = tg_b[s];
            if (s == 0) {
                part += start_tr[t] + em_b[t];
            } else {
                int tp = tg_b[s - 1];
                float v = trans[tp * NT + t] + em_b[s * NT + t];
                part += m ? v : 0.f;
            }
        }
#pragma unroll
        for (int d = 32; d; d >>= 1) {
            part   += __shfl_xor(part, d);
            mcount += __shfl_xor(mcount, d);
        }
        if (j == 0) score_lds = part + end_tr[tg_b[mcount - 1]];
    } else {
        // ---------------- chain: r^T <- r^T M_c, c = PCH_-1..0 ----------------
        float r = __expf(end_tr[j]);
        r_lds[j] = r;
        __threadfence_block();
        int X = 0;

        uint4 cur[8], nxt[8];
#pragma unroll
        for (int u = 0; u < 8; ++u)
            cur[u] = *(const uint4*)(mb + (size_t)(PCH_ - 1) * 4096 + j * 64 + u * 8);

        for (int c = PCH_ - 1; c >= 0; --c) {
            if (c > 0) {
#pragma unroll
                for (int u = 0; u < 8; ++u)
                    nxt[u] = *(const uint4*)(mb + (size_t)(c - 1) * 4096 + j * 64 + u * 8);
            }
            float a0 = 0.f, a1 = 0.f, a2 = 0.f, a3 = 0.f;
#pragma unroll
            for (int u = 0; u < 8; ++u) {
                uint4 q = cur[u];
                f32x4 ra = *(const f32x4*)&r_lds[u * 8];
                f32x4 rb = *(const f32x4*)&r_lds[u * 8 + 4];
                a0 = fmaf(ra[0], __uint_as_float(q.x << 16),         a0);
                a1 = fmaf(ra[1], __uint_as_float(q.x & 0xffff0000u), a1);
                a2 = fmaf(ra[2], __uint_as_float(q.y << 16),         a2);
                a3 = fmaf(ra[3], __uint_as_float(q.y & 0xffff0000u), a3);
                a0 = fmaf(rb[0], __uint_as_float(q.z << 16),         a0);
                a1 = fmaf(rb[1], __uint_as_float(q.z & 0xffff0000u), a1);
                a2 = fmaf(rb[2], __uint_as_float(q.w << 16),         a2);
                a3 = fmaf(rb[3], __uint_as_float(q.w & 0xffff0000u), a3);
            }
            float rn = (a0 + a1) + (a2 + a3);
            unsigned eb = (__builtin_amdgcn_readfirstlane((int)__float_as_uint(rn)) >> 23) & 0xffu;
            r = rn * __uint_as_float((254u - eb) << 23);   // * 2^(127-eb)
            X += (int)eb - 127;
            r_lds[j] = r;
            __threadfence_block();
#pragma unroll
            for (int u = 0; u < 8; ++u) cur[u] = nxt[u];
        }

        float u0 = __expf(start_tr[j] + em_b[j]);
        float v = r * u0;
#pragma unroll
        for (int d = 32; d; d >>= 1) v += __shfl_xor(v, d);
        denom = __logf(v) + (float)(X + 7 * (SEQ - 1)) * 0.6931471805599453f;
    }

    __syncthreads();  // score_lds ready

    if (wave == 0 && j == 0) {
        float llh = denom - score_lds;
        atomicAdd(&ws_head[0], llh * (1.0f / BATCH));
        __threadfence();
        unsigned old = atomicAdd((unsigned*)ws_head + 1, 1u);
        if (old == BATCH - 1) {
            __threadfence();
            out[0] = atomicAdd(&ws_head[0], 0.0f);  // coherent read of final sum
        }
    }
}

extern "C" void kernel_launch(void* const* d_in, const int* in_sizes, int n_in,
                              void* d_out, int out_size, void* d_ws, size_t ws_size,
                              hipStream_t stream) {
    const float* emissions = (const float*)d_in[0];
    const int*   tags      = (const int*)d_in[1];
    const int*   mask      = (const int*)d_in[2];
    const float* start_tr  = (const float*)d_in[3];
    const float* end_tr    = (const float*)d_in[4];
    const float* trans     = (const float*)d_in[5];

    float* ws_head = (float*)d_ws;                                 // sum/cnt/dummy
    unsigned short* mats = (unsigned short*)((char*)d_ws + 4096);  // bf16 chunk mats (16.8 MB)

    // PCH=8, CLEN=64, column-split: 2 waves/chunk, 2 chunks/WG ->
    // grid 4 x 256 = 1024 WGs = 4 WGs/CU = 16 waves/CU.
    crf_chunk_split<8, 64><<<dim3(4, BATCH), 256, 0, stream>>>(emissions, trans, mats, ws_head);
    crf_combine_kernel<8><<<BATCH, 256, 0, stream>>>(emissions, tags, mask,
                                                     start_tr, end_tr, trans, mats,
                                                     ws_head, (float*)d_out);
}